// Round 8
// baseline (946.927 us; speedup 1.0000x reference)
//
#include <hip/hip_runtime.h>
#include <hip/hip_cooperative_groups.h>

namespace cg = cooperative_groups;

constexpr int kB   = 8;
constexpr int kN   = 64;
constexpr int kE   = 192;
constexpr int kDin = 1024;
constexpr int kDp  = 256;
constexpr int kNN  = 4096;
constexpr float kTauInv = 20.0f;

// ---------------------------------------------------------------------------
// Projection GEMM, K-split (z=4), double-buffered LDS, partial out (no bias).
// Block (0,0,0) also zeroes stats.
// ---------------------------------------------------------------------------
__global__ __launch_bounds__(256) void gemm_proj(
    const float* __restrict__ x1, const float* __restrict__ x2,
    const float* __restrict__ e1, const float* __restrict__ e2,
    const float* __restrict__ Wp, float* __restrict__ P,
    float* __restrict__ stats)
{
    const int rt = blockIdx.y, ct = blockIdx.x, z = blockIdx.z;
    const int tid = threadIdx.x;
    if (blockIdx.x == 0 && blockIdx.y == 0 && blockIdx.z == 0) {
        for (int i = tid; i < 2048; i += 256) stats[i] = 0.f;
    }
    const int tx = tid & 15, ty = tid >> 4;
    const int grow0 = rt * 64, col0 = ct * 64;

    const float* src; int lrow0;
    if (rt < 8)       { src = x1; lrow0 = grow0; }
    else if (rt < 16) { src = x2; lrow0 = grow0 - 512; }
    else if (rt < 40) { src = e1; lrow0 = grow0 - 1024; }
    else              { src = e2; lrow0 = grow0 - 2560; }

    __shared__ float As[2][16][68];
    __shared__ float Ws[2][16][68];

    const int arow = tid >> 2, acol = (tid & 3) * 4;
    const int wrow = tid >> 4, wcol = (tid & 15) * 4;

    const float* Abase = src + (size_t)(lrow0 + arow) * kDin + z * 256 + acol;
    const float* Wbase = Wp + (size_t)(z * 256 + wrow) * kDp + col0 + wcol;

    float4 a4 = *(const float4*)Abase;
    float4 w4 = *(const float4*)Wbase;

    float acc[4][4] = {};

    for (int c = 0; c < 16; ++c) {
        const int cur = c & 1;
        As[cur][acol + 0][arow] = a4.x;
        As[cur][acol + 1][arow] = a4.y;
        As[cur][acol + 2][arow] = a4.z;
        As[cur][acol + 3][arow] = a4.w;
        *(float4*)&Ws[cur][wrow][wcol] = w4;
        __syncthreads();
        if (c < 15) {
            a4 = *(const float4*)(Abase + (c + 1) * 16);
            w4 = *(const float4*)(Wbase + (size_t)(c + 1) * 16 * kDp);
        }
#pragma unroll
        for (int kk = 0; kk < 16; ++kk) {
            float4 av = *(const float4*)&As[cur][kk][ty * 4];
            float4 wv = *(const float4*)&Ws[cur][kk][tx * 4];
            float a[4] = {av.x, av.y, av.z, av.w};
            float w[4] = {wv.x, wv.y, wv.z, wv.w};
#pragma unroll
            for (int i = 0; i < 4; ++i)
#pragma unroll
                for (int j = 0; j < 4; ++j)
                    acc[i][j] += a[i] * w[j];
        }
    }
    float* Pz = P + (size_t)z * 1048576;
#pragma unroll
    for (int i = 0; i < 4; ++i)
#pragma unroll
        for (int j = 0; j < 4; ++j)
            Pz[(size_t)(grow0 + ty * 4 + i) * kDp + col0 + tx * 4 + j] = acc[i][j];
}

__global__ __launch_bounds__(256) void reduce_bias_stats(
    const float* __restrict__ P, const float* __restrict__ bp,
    float* __restrict__ hbuf, float* __restrict__ stats)
{
    const int t = threadIdx.x;
    const int r0 = blockIdx.x * 16;
    const int seg = (r0 < 512) ? 0 : (r0 < 1024 ? 1 : (r0 < 2560 ? 2 : 3));
    const float bb = bp[t];
    float s = 0.f, s2 = 0.f;
#pragma unroll
    for (int rr = 0; rr < 16; ++rr) {
        size_t o = (size_t)(r0 + rr) * kDp + t;
        float v = P[o] + P[o + 1048576] + P[o + 2097152] + P[o + 3145728] + bb;
        hbuf[o] = v;
        s += v; s2 += v * v;
    }
    atomicAdd(&stats[seg * 512 + t], s);
    atomicAdd(&stats[seg * 512 + 256 + t], s2);
}

__global__ __launch_bounds__(256) void bn_norm_l2(float* hbuf,
                                                  const float* __restrict__ stats,
                                                  const float* __restrict__ gamma,
                                                  const float* __restrict__ beta)
{
    int r = blockIdx.x, tid = threadIdx.x;
    int seg = (r < 512) ? 0 : (r < 1024 ? 1 : (r < 2560 ? 2 : 3));
    float n = (seg < 2) ? 512.f : 1536.f;
    float mu   = stats[seg * 512 + tid] / n;
    float var  = stats[seg * 512 + 256 + tid] / n - mu * mu;
    float istd = rsqrtf(var + 1e-5f);
    float v = hbuf[(size_t)r * kDp + tid];
    float p = fmaxf((v - mu) * istd * gamma[tid] + beta[tid], 0.f);
    float ss = p * p;
#pragma unroll
    for (int o = 32; o >= 1; o >>= 1) ss += __shfl_xor(ss, o);
    __shared__ float wsum[4];
    if ((tid & 63) == 0) wsum[tid >> 6] = ss;
    __syncthreads();
    float tot = wsum[0] + wsum[1] + wsum[2] + wsum[3];
    float scale = 1.f / fmaxf(sqrtf(tot), 1e-12f);
    hbuf[(size_t)r * kDp + tid] = p * scale;
}

// ---------------------------------------------------------------------------
// Sinkhorn inner loop via dual potentials, 4 lanes/row (threads t < NR*4).
// ---------------------------------------------------------------------------
template <int NR>
__device__ inline void sink_iter4(float (*mat)[68], float* fL, float* gL, int t)
{
    constexpr int MAXK = (NR + 3) / 4;
    const int r = t >> 2, s = t & 3;
    const bool act = r < NR;
    float Lrow[MAXK], Lcol[MAXK];
#pragma unroll
    for (int k = 0; k < MAXK; ++k) {
        int c = s + 4 * k;
        bool ok = act && c < NR;
        Lrow[k] = ok ? mat[r][c] : -1e30f;
        Lcol[k] = ok ? mat[c][r] : -1e30f;
    }
    if (t < NR) { fL[t] = 0.f; gL[t] = 0.f; }
    __syncthreads();

    float tv[MAXK];
    for (int it = 0; it < 10; ++it) {
        float mx = -1e30f;
#pragma unroll
        for (int k = 0; k < MAXK; ++k) {
            int c = s + 4 * k;
            tv[k] = (c < NR) ? Lrow[k] + gL[c] : -1e30f;
            mx = fmaxf(mx, tv[k]);
        }
        mx = fmaxf(mx, __shfl_xor(mx, 1));
        mx = fmaxf(mx, __shfl_xor(mx, 2));
        float sum = 0.f;
#pragma unroll
        for (int k = 0; k < MAXK; ++k) {
            int c = s + 4 * k;
            if (c < NR) sum += __expf(tv[k] - mx);
        }
        sum += __shfl_xor(sum, 1);
        sum += __shfl_xor(sum, 2);
        if (act && s == 0) fL[r] = -(mx + __logf(sum));
        __syncthreads();

        mx = -1e30f;
#pragma unroll
        for (int k = 0; k < MAXK; ++k) {
            int c = s + 4 * k;
            tv[k] = (c < NR) ? Lcol[k] + fL[c] : -1e30f;
            mx = fmaxf(mx, tv[k]);
        }
        mx = fmaxf(mx, __shfl_xor(mx, 1));
        mx = fmaxf(mx, __shfl_xor(mx, 2));
        sum = 0.f;
#pragma unroll
        for (int k = 0; k < MAXK; ++k) {
            int c = s + 4 * k;
            if (c < NR) sum += __expf(tv[k] - mx);
        }
        sum += __shfl_xor(sum, 1);
        sum += __shfl_xor(sum, 2);
        if (act && s == 0) gL[r] = -(mx + __logf(sum));
        __syncthreads();
    }
}

// ---------------------------------------------------------------------------
// Cooperative tail kernel args
// ---------------------------------------------------------------------------
struct CoopArgs {
    const int *s1, *d1, *s2, *d2;
    const float *hbuf;
    float *Kp, *Ke;
    const float *W0, *b0, *S0, *c0;
    const float *W1, *b1, *S1, *c1;
    const float *W2, *b2, *S2, *c2;
    const float *Wc, *bc, *binv;
    float *xA, *xB, *vbuf;
    int *degcnt;
    int *goff1, *goff2, *gcoff1, *gcoff2;
    int *gil1, *gjl2, *gclst1, *gclst2, *grp1, *grp2;
    unsigned *maxbuf;
    float *outp;
};

__device__ __forceinline__ void layer17_phase(
    const CoopArgs& A, const float* Wg, const float* bg, const float* Sg,
    const float* cg, const float* xin, float* xout, int* ubuf, int t)
{
    float* WL = (float*)ubuf;                 // 272
    float* bL = WL + 272;                     // 16
    float* SL = bL + 16;                      // 16
    int*   jd2 = (int*)(SL + 16);             // 192
    int*   il  = jd2 + 192;                   // 192
    float (*msgT)[18] = (float (*)[18])(il + 192); // 1152

    for (int u = blockIdx.x; u < 512; u += 256) {
        const int b = u >> 6, r2 = u & 63;
        const float* Keb = A.Ke + (size_t)b * kE * kE;
        const float* xb  = xin + (size_t)b * kNN * 17;
        float*       xo  = xout + (size_t)b * kNN * 17;

        for (int k = t; k < 272; k += 320) WL[k] = Wg[k];
        if (t < 16) { bL[t] = bg[t]; SL[t] = Sg[t]; }
        const int j0 = A.goff2[b * 65 + r2];
        const int n2 = A.goff2[b * 65 + r2 + 1] - j0;
        for (int k = t; k < n2; k += 320) jd2[k] = A.gjl2[b * kE + j0 + k];
        for (int k = t; k < kE; k += 320) il[k] = A.gil1[b * kE + k];
        __syncthreads();

        if (t < 256) {
            const int r1 = t >> 2, lane = t & 3;
            const int i0 = A.goff1[b * 65 + r1], i1 = A.goff1[b * 65 + r1 + 1];
            float acc[5];
#pragma unroll
            for (int cc = 0; cc < 5; ++cc) acc[cc] = 0.f;
            for (int k = 0; k < n2; ++k) {
                int pk = jd2[k], j = pk >> 8, dd2 = pk & 255;
                const float* xrow = xb + (size_t)(dd2 * 64) * 17;
                for (int m = i0; m < i1; ++m) {
                    int pi = il[m], i = pi >> 8, dd1 = pi & 255;
                    if (dd2 == r2 && dd1 == r1) continue;
                    float kv = Keb[(size_t)i * kE + j];
                    const float* xc = xrow + dd1 * 17;
#pragma unroll
                    for (int cc = 0; cc < 5; ++cc) {
                        int c = lane + cc * 4;
                        if (c < 17) acc[cc] += kv * xc[c];
                    }
                }
            }
#pragma unroll
            for (int cc = 0; cc < 5; ++cc) {
                int c = lane + cc * 4;
                if (c < 17) msgT[r1][c] = acc[cc];
            }
        }
        __syncthreads();

        if (t < 256) {
            const int r1 = t >> 2, lane = t & 3;
            const int row = r2 * 64 + r1;
            const float kd = A.Kp[(size_t)b * kNN + r1 * 64 + r2];
            const float dg = fmaxf((float)(A.degcnt[b * kNN + row] + (kd > 0.f ? 1 : 0)), 1.f);
            const float inv = 1.f / dg;
            const float* xr = xb + (size_t)row * 17;
            float m[17];
#pragma unroll
            for (int c = 0; c < 17; ++c)
                m[c] = (msgT[r1][c] + kd * xr[c]) * inv;
            float vpart = 0.f;
#pragma unroll
            for (int ff = 0; ff < 4; ++ff) {
                int f = lane * 4 + ff;
                float a = bL[f];
#pragma unroll
                for (int c = 0; c < 17; ++c) a += m[c] * WL[c * 16 + f];
                float h = fmaxf(a, 0.f);
                xo[(size_t)row * 17 + f] = h;
                vpart += h * SL[f];
            }
            vpart += __shfl_xor(vpart, 1);
            vpart += __shfl_xor(vpart, 2);
            if (lane == 0) A.vbuf[b * kNN + row] = vpart + cg[0];
        }
        __syncthreads();
    }
}

__device__ __forceinline__ void sink64_phase(const CoopArgs& A, float* xout,
                                             int* ubuf, int t)
{
    if (blockIdx.x < 8) {
        const int b = blockIdx.x;
        float (*mat)[68] = (float (*)[68])ubuf;      // 64x68
        float* fL = (float*)(ubuf + 64 * 68);        // 65
        float* gL = fL + 65;
        for (int idx = t; idx < kNN; idx += 320) {
            int q = idx >> 6, p = idx & 63;
            mat[p][q] = A.vbuf[b * kNN + q * 64 + p] * kTauInv;
        }
        __syncthreads();
        sink_iter4<64>(mat, fL, gL, t);
        float* xo = xout + (size_t)b * kNN * 17;
        for (int idx = t; idx < kNN; idx += 320) {
            int p = idx >> 6, q = idx & 63;
            xo[(size_t)(q * 64 + p) * 17 + 16] = __expf(mat[p][q] + fL[p] + gL[q]);
        }
    }
}

__global__ __launch_bounds__(320) void coop_tail(CoopArgs A)
{
    cg::grid_group grid = cg::this_grid();
    const int t = threadIdx.x;
    __shared__ __align__(16) int ubuf[10240];   // 40 KB phase-union scratch

    // ================= P0: similarity GEMMs (320 units) =================
    {
        float (*Xs)[36] = (float (*)[36])ubuf;
        float (*Ys)[36] = (float (*)[36])(ubuf + 32 * 36);
        for (int u = blockIdx.x; u < 320; u += 256) {
            const int id = u % 40, b = u / 40;
            int mt, nt, ldo; const float *X, *Y; float* outp; float scale;
            if (id < 4) {
                mt = (id >> 1) * 32; nt = (id & 1) * 32; ldo = 64;
                X = A.hbuf + (size_t)b * 64 * kDp;
                Y = A.hbuf + (512 + (size_t)b * 64) * kDp;
                outp = A.Kp + (size_t)b * 4096; scale = 1.0f;
            } else {
                int e = id - 4;
                mt = (e / 6) * 32; nt = (e % 6) * 32; ldo = 192;
                X = A.hbuf + (1024 + (size_t)b * 192) * kDp;
                Y = A.hbuf + (2560 + (size_t)b * 192) * kDp;
                outp = A.Ke + (size_t)b * 36864; scale = 0.5f;
            }
            const int row = t >> 3, kq = t & 7;
            const int ty = t >> 4, tx = t & 15;
            float acc[2][2] = {};
            for (int k0 = 0; k0 < kDp; k0 += 32) {
                if (t < 256) {
                    float4 xa = *(const float4*)(X + (size_t)(mt + row) * kDp + k0 + kq * 4);
                    float4 ya = *(const float4*)(Y + (size_t)(nt + row) * kDp + k0 + kq * 4);
                    Xs[kq * 4 + 0][row] = xa.x; Xs[kq * 4 + 1][row] = xa.y;
                    Xs[kq * 4 + 2][row] = xa.z; Xs[kq * 4 + 3][row] = xa.w;
                    Ys[kq * 4 + 0][row] = ya.x; Ys[kq * 4 + 1][row] = ya.y;
                    Ys[kq * 4 + 2][row] = ya.z; Ys[kq * 4 + 3][row] = ya.w;
                }
                __syncthreads();
                if (t < 256) {
#pragma unroll
                    for (int kk = 0; kk < 32; ++kk) {
                        float2 xv = *(const float2*)&Xs[kk][ty * 2];
                        float2 yv = *(const float2*)&Ys[kk][tx * 2];
                        acc[0][0] += xv.x * yv.x; acc[0][1] += xv.x * yv.y;
                        acc[1][0] += xv.y * yv.x; acc[1][1] += xv.y * yv.y;
                    }
                }
                __syncthreads();
            }
            if (t < 256) {
#pragma unroll
                for (int i = 0; i < 2; ++i)
#pragma unroll
                    for (int j = 0; j < 2; ++j)
                        outp[(size_t)(mt + ty * 2 + i) * ldo + nt + tx * 2 + j] = scale * acc[i][j];
            }
            __syncthreads();
        }
    }
    __threadfence();
    grid.sync();

    // ================= P1: CSR + class reps (8 blocks) =================
    if (blockIdx.x == 8 && t == 0) *A.maxbuf = 0u;
    if (blockIdx.x < 8) {
        const int b = blockIdx.x;
        int* km1 = ubuf;
        int* km2 = ubuf + 4096;
        int* aux = ubuf + 8192;
        int* cnt1 = aux;        int* cnt2 = aux + 64;
        int* pos1 = aux + 128;  int* pos2 = aux + 192;
        int* ccnt1 = aux + 256; int* ccnt2 = aux + 448;
        int* cpos1 = aux + 640; int* cpos2 = aux + 832;
        int* es1 = aux + 1024;  int* es2 = aux + 1216;
        int* rp1 = aux + 1408;  int* rp2 = aux + 1600;

        for (int i = t; i < 4096; i += 320) {
            km1[i] = 0x7fffffff; km2[i] = 0x7fffffff;
            A.degcnt[b * kNN + i] = 0;
        }
        if (t < 64) { cnt1[t] = 0; cnt2[t] = 0; }
        if (t < kE) { ccnt1[t] = 0; ccnt2[t] = 0; }
        __syncthreads();
        if (t < kE) {
            int v1 = A.s1[b * kE + t], v2 = A.s2[b * kE + t];
            es1[t] = v1; es2[t] = v2;
            atomicAdd(&cnt1[v1], 1);
            atomicAdd(&cnt2[v2], 1);
            atomicMin(&km1[v1 * 64 + A.d1[b * kE + t]], t);
            atomicMin(&km2[v2 * 64 + A.d2[b * kE + t]], t);
        }
        __syncthreads();
        if (t < kE) {
            int r1 = km1[es1[t] * 64 + A.d1[b * kE + t]];
            int r2 = km2[es2[t] * 64 + A.d2[b * kE + t]];
            rp1[t] = r1; rp2[t] = r2;
            A.grp1[b * kE + t] = r1; A.grp2[b * kE + t] = r2;
            atomicAdd(&ccnt1[r1], 1);
            atomicAdd(&ccnt2[r2], 1);
        }
        __syncthreads();
        if (t == 0)        { int a = 0; for (int v = 0; v < 64; ++v) { A.goff1[b * 65 + v] = a; pos1[v] = a; a += cnt1[v]; } A.goff1[b * 65 + 64] = kE; }
        else if (t == 64)  { int a = 0; for (int v = 0; v < 64; ++v) { A.goff2[b * 65 + v] = a; pos2[v] = a; a += cnt2[v]; } A.goff2[b * 65 + 64] = kE; }
        else if (t == 128) { int a = 0; for (int v = 0; v < kE; ++v) { A.gcoff1[b * 193 + v] = a; cpos1[v] = a; a += ccnt1[v]; } A.gcoff1[b * 193 + kE] = kE; }
        else if (t == 192) { int a = 0; for (int v = 0; v < kE; ++v) { A.gcoff2[b * 193 + v] = a; cpos2[v] = a; a += ccnt2[v]; } A.gcoff2[b * 193 + kE] = kE; }
        __syncthreads();
        if (t < kE) {
            int p = atomicAdd(&pos1[es1[t]], 1);
            A.gil1[b * kE + p] = (t << 8) | A.d1[b * kE + t];
            int q = atomicAdd(&pos2[es2[t]], 1);
            A.gjl2[b * kE + q] = (t << 8) | A.d2[b * kE + t];
            int cp = atomicAdd(&cpos1[rp1[t]], 1); A.gclst1[b * kE + cp] = t;
            int cq = atomicAdd(&cpos2[rp2[t]], 1); A.gclst2[b * kE + cq] = t;
        }
    }
    __threadfence();
    grid.sync();

    // ================= P2: pair degree count (256 blocks) =================
    {
        const int b = blockIdx.x >> 5;
        int* es1 = ubuf;        int* ed1 = ubuf + 192;
        int* es2 = ubuf + 384;  int* ed2 = ubuf + 576;
        int* rp1 = ubuf + 768;  int* rp2 = ubuf + 960;
        int* cl1 = ubuf + 1152; int* cl2 = ubuf + 1344;
        int* co1 = ubuf + 1536; int* co2 = ubuf + 1732;
        for (int i = t; i < kE; i += 320) {
            es1[i] = A.s1[b * kE + i]; ed1[i] = A.d1[b * kE + i];
            es2[i] = A.s2[b * kE + i]; ed2[i] = A.d2[b * kE + i];
            rp1[i] = A.grp1[b * kE + i]; rp2[i] = A.grp2[b * kE + i];
            cl1[i] = A.gclst1[b * kE + i]; cl2[i] = A.gclst2[b * kE + i];
        }
        for (int i = t; i < kE + 1; i += 320) {
            co1[i] = A.gcoff1[b * 193 + i]; co2[i] = A.gcoff2[b * 193 + i];
        }
        __syncthreads();
        const float* Keb = A.Ke + (size_t)b * kE * kE;
        const int base = (blockIdx.x & 31) * 1152;
        for (int k = t; k < 1152; k += 320) {
            int idx = base + k;
            int i = idx / kE, j = idx - i * kE;
            if (rp1[i] != i || rp2[j] != j) continue;
            float sum = 0.f;
            for (int m = co1[i]; m < co1[i + 1]; ++m) {
                const float* kr = Keb + (size_t)cl1[m] * kE;
                for (int n = co2[j]; n < co2[j + 1]; ++n) sum += kr[cl2[n]];
            }
            int r = es2[j] * 64 + es1[i];
            int c = ed2[j] * 64 + ed1[i];
            if (r != c && sum > 0.f) atomicAdd(&A.degcnt[b * kNN + r], 1);
        }
    }
    __threadfence();
    grid.sync();

    // ================= P3: layer 0 (C=1) =================
    {
        float* KpL = (float*)ubuf;                 // 4096
        int*   jd2 = ubuf + 4096;                  // 192
        int*   il  = ubuf + 4288;                  // 192
        float* WL  = (float*)(ubuf + 4480);        // 16
        float* bL  = WL + 16;                      // 16
        float* SL  = bL + 16;                      // 16
        float (*msgT)[1] = (float (*)[1])(SL + 16);
        for (int u = blockIdx.x; u < 512; u += 256) {
            const int b = u >> 6, r2 = u & 63;
            const float* Keb = A.Ke + (size_t)b * kE * kE;
            float* xo = A.xA + (size_t)b * kNN * 17;
            for (int i = t; i < 4096; i += 320) KpL[i] = A.Kp[(size_t)b * 4096 + i];
            if (t < 16) { WL[t] = A.W0[t]; bL[t] = A.b0[t]; SL[t] = A.S0[t]; }
            const int j0 = A.goff2[b * 65 + r2];
            const int n2 = A.goff2[b * 65 + r2 + 1] - j0;
            for (int k = t; k < n2; k += 320) jd2[k] = A.gjl2[b * kE + j0 + k];
            for (int k = t; k < kE; k += 320) il[k] = A.gil1[b * kE + k];
            __syncthreads();
            if (t < 256) {
                const int r1 = t >> 2, lane = t & 3;
                const int i0 = A.goff1[b * 65 + r1], i1 = A.goff1[b * 65 + r1 + 1];
                float acc = 0.f;
                for (int k = 0; k < n2; ++k) {
                    int pk = jd2[k], j = pk >> 8, dd2 = pk & 255;
                    for (int m = i0 + lane; m < i1; m += 4) {
                        int pi = il[m], i = pi >> 8, dd1 = pi & 255;
                        if (dd2 == r2 && dd1 == r1) continue;
                        acc += Keb[(size_t)i * kE + j] * KpL[dd1 * 64 + dd2];
                    }
                }
                acc += __shfl_xor(acc, 1);
                acc += __shfl_xor(acc, 2);
                if (lane == 0) msgT[r1][0] = acc;
            }
            __syncthreads();
            if (t < 256) {
                const int r1 = t >> 2, lane = t & 3;
                const int row = r2 * 64 + r1;
                const float kd = KpL[r1 * 64 + r2];
                const float dg = fmaxf((float)(A.degcnt[b * kNN + row] + (kd > 0.f ? 1 : 0)), 1.f);
                const float mv = (msgT[r1][0] + kd * kd) / dg;
                float vpart = 0.f;
#pragma unroll
                for (int ff = 0; ff < 4; ++ff) {
                    int f = lane * 4 + ff;
                    float h = fmaxf(mv * WL[f] + bL[f], 0.f);
                    xo[(size_t)row * 17 + f] = h;
                    vpart += h * SL[f];
                }
                vpart += __shfl_xor(vpart, 1);
                vpart += __shfl_xor(vpart, 2);
                if (lane == 0) A.vbuf[b * kNN + row] = vpart + A.c0[0];
            }
            __syncthreads();
        }
    }
    __threadfence();
    grid.sync();

    // ================= P4: sinkhorn 0 =================
    sink64_phase(A, A.xA, ubuf, t);
    __threadfence();
    grid.sync();

    // ================= P5: layer 1 =================
    layer17_phase(A, A.W1, A.b1, A.S1, A.c1, A.xA, A.xB, ubuf, t);
    __threadfence();
    grid.sync();

    // ================= P6: sinkhorn 1 =================
    sink64_phase(A, A.xB, ubuf, t);
    __threadfence();
    grid.sync();

    // ================= P7: layer 2 =================
    layer17_phase(A, A.W2, A.b2, A.S2, A.c2, A.xB, A.xA, ubuf, t);
    __threadfence();
    grid.sync();

    // ================= P8: sinkhorn 2 =================
    sink64_phase(A, A.xA, ubuf, t);
    __threadfence();
    grid.sync();

    // ================= P9: final projection + 65x65 sinkhorn =================
    if (blockIdx.x < 8) {
        const int b = blockIdx.x;
        float (*mat)[68] = (float (*)[68])ubuf;     // 65x68
        float* fL = (float*)(ubuf + 65 * 68);       // 65
        float* gL = fL + 65;                        // 65
        float* WcL = gL + 65;                       // 17
        if (t < 17) WcL[t] = A.Wc[t];
        __syncthreads();
        const float bcv = A.bc[0], binvv = A.binv[0];
        const float* xa = A.xA + (size_t)b * kNN * 17;
        for (int idx = t; idx < kNN; idx += 320) {
            int p = idx >> 6, q = idx & 63;
            const float* xr = xa + (size_t)(q * 64 + p) * 17;
            float v = bcv;
#pragma unroll
            for (int c = 0; c < 17; ++c) v += xr[c] * WcL[c];
            mat[p][q] = v;
        }
        if (t < 65) { mat[t][64] = binvv; mat[64][t] = binvv; }
        __syncthreads();
        sink_iter4<65>(mat, fL, gL, t);
        for (int idx = t; idx < kNN; idx += 320) {
            int p = idx >> 6, q = idx & 63;
            A.outp[(size_t)b * kNN + p * 64 + q] = __expf(mat[p][q] + fL[p] + gL[q]);
        }
    }
    __threadfence();
    grid.sync();

    // ================= P10: global max =================
    if (blockIdx.x < 128 && t < 256) {
        int gid = blockIdx.x * 256 + t;
        float v = A.outp[gid];
#pragma unroll
        for (int o = 32; o >= 1; o >>= 1) v = fmaxf(v, __shfl_xor(v, o));
        if ((t & 63) == 0) atomicMax(A.maxbuf, __float_as_uint(v));
    }
    __threadfence();
    grid.sync();

    // ================= P11: scale =================
    if (blockIdx.x < 128 && t < 256) {
        int gid = blockIdx.x * 256 + t;
        A.outp[gid] = A.outp[gid] / __uint_as_float(*A.maxbuf);
    }
}

// ---------------------------------------------------------------------------
extern "C" void kernel_launch(void* const* d_in, const int* in_sizes, int n_in,
                              void* d_out, int out_size, void* d_ws, size_t ws_size,
                              hipStream_t stream)
{
    (void)in_sizes; (void)n_in; (void)out_size; (void)ws_size;

    const float* x1    = (const float*)d_in[0];
    const float* x2    = (const float*)d_in[1];
    const float* e1    = (const float*)d_in[2];
    const float* e2    = (const float*)d_in[3];
    const float* Wp    = (const float*)d_in[4];
    const float* bp    = (const float*)d_in[5];
    const float* gamma = (const float*)d_in[6];
    const float* beta  = (const float*)d_in[7];

    float* out = (float*)d_out;
    float* wsf = (float*)d_ws;

    float* hbuf  = wsf;                    // 1,048,576
    float* P     = hbuf + 1048576;         // 4,194,304
    float* Kp    = P + 4194304;            // 32768
    float* Ke    = Kp + 32768;             // 294912
    float* xA    = Ke + 294912;            // 557056
    float* xB    = xA + 557056;            // 557056
    float* vbuf  = xB + 557056;            // 32768
    float* stats = vbuf + 32768;           // 2048
    int*   degcnt = (int*)(stats + 2048);  // 32768
    int*   goff1 = degcnt + 32768;         // 520
    int*   goff2 = goff1 + 520;            // 520
    int*   gcoff1 = goff2 + 520;           // 1544
    int*   gcoff2 = gcoff1 + 1544;         // 1544
    int*   gil1 = gcoff2 + 1544;           // 1536
    int*   gjl2 = gil1 + 1536;             // 1536
    int*   gclst1 = gjl2 + 1536;           // 1536
    int*   gclst2 = gclst1 + 1536;         // 1536
    int*   grp1 = gclst2 + 1536;           // 1536
    int*   grp2 = grp1 + 1536;             // 1536
    unsigned* maxbuf = (unsigned*)(grp2 + 1536);

    // ---- front: projection GEMM + fused reduce/stats + BN ----
    gemm_proj<<<dim3(4, 64, 4), 256, 0, stream>>>(x1, x2, e1, e2, Wp, P, stats);
    reduce_bias_stats<<<256, 256, 0, stream>>>(P, bp, hbuf, stats);
    bn_norm_l2<<<4096, 256, 0, stream>>>(hbuf, stats, gamma, beta);

    // ---- cooperative tail: gemm_sim .. normalize ----
    CoopArgs ca;
    ca.s1 = (const int*)d_in[23]; ca.d1 = (const int*)d_in[24];
    ca.s2 = (const int*)d_in[25]; ca.d2 = (const int*)d_in[26];
    ca.hbuf = hbuf; ca.Kp = Kp; ca.Ke = Ke;
    ca.W0 = (const float*)d_in[8];  ca.b0 = (const float*)d_in[9];
    ca.S0 = (const float*)d_in[10]; ca.c0 = (const float*)d_in[11];
    ca.W1 = (const float*)d_in[12]; ca.b1 = (const float*)d_in[13];
    ca.S1 = (const float*)d_in[14]; ca.c1 = (const float*)d_in[15];
    ca.W2 = (const float*)d_in[16]; ca.b2 = (const float*)d_in[17];
    ca.S2 = (const float*)d_in[18]; ca.c2 = (const float*)d_in[19];
    ca.Wc = (const float*)d_in[20]; ca.bc = (const float*)d_in[21];
    ca.binv = (const float*)d_in[22];
    ca.xA = xA; ca.xB = xB; ca.vbuf = vbuf; ca.degcnt = degcnt;
    ca.goff1 = goff1; ca.goff2 = goff2; ca.gcoff1 = gcoff1; ca.gcoff2 = gcoff2;
    ca.gil1 = gil1; ca.gjl2 = gjl2; ca.gclst1 = gclst1; ca.gclst2 = gclst2;
    ca.grp1 = grp1; ca.grp2 = grp2;
    ca.maxbuf = maxbuf; ca.outp = out;

    void* kargs[] = { &ca };
    hipLaunchCooperativeKernel((const void*)coop_tail, dim3(256), dim3(320),
                               kargs, 0, stream);
}

// Round 10
// 378.238 us; speedup vs baseline: 2.5035x; 2.5035x over previous
//
#include <hip/hip_runtime.h>

constexpr int kB   = 8;
constexpr int kN   = 64;
constexpr int kE   = 192;
constexpr int kDin = 1024;
constexpr int kDp  = 256;
constexpr int kNN  = 4096;
constexpr float kTauInv = 20.0f;

// ---------------------------------------------------------------------------
// Projection GEMM, K-split (z=4), double-buffered LDS, partial out (no bias).
// Block (0,0,0) also zeroes stats (consumed 1 kernel later).
// ---------------------------------------------------------------------------
__global__ __launch_bounds__(256) void gemm_proj(
    const float* __restrict__ x1, const float* __restrict__ x2,
    const float* __restrict__ e1, const float* __restrict__ e2,
    const float* __restrict__ Wp, float* __restrict__ P,
    float* __restrict__ stats)
{
    const int rt = blockIdx.y, ct = blockIdx.x, z = blockIdx.z;
    const int tid = threadIdx.x;
    if (blockIdx.x == 0 && blockIdx.y == 0 && blockIdx.z == 0) {
        for (int i = tid; i < 2048; i += 256) stats[i] = 0.f;
    }
    const int tx = tid & 15, ty = tid >> 4;
    const int grow0 = rt * 64, col0 = ct * 64;

    const float* src; int lrow0;
    if (rt < 8)       { src = x1; lrow0 = grow0; }
    else if (rt < 16) { src = x2; lrow0 = grow0 - 512; }
    else if (rt < 40) { src = e1; lrow0 = grow0 - 1024; }
    else              { src = e2; lrow0 = grow0 - 2560; }

    __shared__ float As[2][16][68];
    __shared__ float Ws[2][16][68];

    const int arow = tid >> 2, acol = (tid & 3) * 4;
    const int wrow = tid >> 4, wcol = (tid & 15) * 4;

    const float* Abase = src + (size_t)(lrow0 + arow) * kDin + z * 256 + acol;
    const float* Wbase = Wp + (size_t)(z * 256 + wrow) * kDp + col0 + wcol;

    float4 a4 = *(const float4*)Abase;
    float4 w4 = *(const float4*)Wbase;

    float acc[4][4] = {};

    for (int c = 0; c < 16; ++c) {
        const int cur = c & 1;
        As[cur][acol + 0][arow] = a4.x;
        As[cur][acol + 1][arow] = a4.y;
        As[cur][acol + 2][arow] = a4.z;
        As[cur][acol + 3][arow] = a4.w;
        *(float4*)&Ws[cur][wrow][wcol] = w4;
        __syncthreads();
        if (c < 15) {
            a4 = *(const float4*)(Abase + (c + 1) * 16);
            w4 = *(const float4*)(Wbase + (size_t)(c + 1) * 16 * kDp);
        }
#pragma unroll
        for (int kk = 0; kk < 16; ++kk) {
            float4 av = *(const float4*)&As[cur][kk][ty * 4];
            float4 wv = *(const float4*)&Ws[cur][kk][tx * 4];
            float a[4] = {av.x, av.y, av.z, av.w};
            float w[4] = {wv.x, wv.y, wv.z, wv.w};
#pragma unroll
            for (int i = 0; i < 4; ++i)
#pragma unroll
                for (int j = 0; j < 4; ++j)
                    acc[i][j] += a[i] * w[j];
        }
    }
    float* Pz = P + (size_t)z * 1048576;
#pragma unroll
    for (int i = 0; i < 4; ++i)
#pragma unroll
        for (int j = 0; j < 4; ++j)
            Pz[(size_t)(grow0 + ty * 4 + i) * kDp + col0 + tx * 4 + j] = acc[i][j];
}

// ---------------------------------------------------------------------------
// Fused: hbuf = sum(P0..P3)+bias  AND  BN stats accumulation (verified R7).
// 256 blocks x 16 rows (segment boundaries are multiples of 16).
// ---------------------------------------------------------------------------
__global__ __launch_bounds__(256) void reduce_bias_stats(
    const float* __restrict__ P, const float* __restrict__ bp,
    float* __restrict__ hbuf, float* __restrict__ stats)
{
    const int t = threadIdx.x;
    const int r0 = blockIdx.x * 16;
    const int seg = (r0 < 512) ? 0 : (r0 < 1024 ? 1 : (r0 < 2560 ? 2 : 3));
    const float bb = bp[t];
    float s = 0.f, s2 = 0.f;
#pragma unroll
    for (int rr = 0; rr < 16; ++rr) {
        size_t o = (size_t)(r0 + rr) * kDp + t;
        float v = P[o] + P[o + 1048576] + P[o + 2097152] + P[o + 3145728] + bb;
        hbuf[o] = v;
        s += v; s2 += v * v;
    }
    atomicAdd(&stats[seg * 512 + t], s);
    atomicAdd(&stats[seg * 512 + 256 + t], s2);
}

__global__ __launch_bounds__(256) void bn_norm_l2(float* hbuf,
                                                  const float* __restrict__ stats,
                                                  const float* __restrict__ gamma,
                                                  const float* __restrict__ beta)
{
    int r = blockIdx.x, tid = threadIdx.x;
    int seg = (r < 512) ? 0 : (r < 1024 ? 1 : (r < 2560 ? 2 : 3));
    float n = (seg < 2) ? 512.f : 1536.f;
    float mu   = stats[seg * 512 + tid] / n;
    float var  = stats[seg * 512 + 256 + tid] / n - mu * mu;
    float istd = rsqrtf(var + 1e-5f);
    float v = hbuf[(size_t)r * kDp + tid];
    float p = fmaxf((v - mu) * istd * gamma[tid] + beta[tid], 0.f);
    float ss = p * p;
#pragma unroll
    for (int o = 32; o >= 1; o >>= 1) ss += __shfl_xor(ss, o);
    __shared__ float wsum[4];
    if ((tid & 63) == 0) wsum[tid >> 6] = ss;
    __syncthreads();
    float tot = wsum[0] + wsum[1] + wsum[2] + wsum[3];
    float scale = 1.f / fmaxf(sqrtf(tot), 1e-12f);
    hbuf[(size_t)r * kDp + tid] = p * scale;
}

// ---------------------------------------------------------------------------
// Combined similarity GEMMs: Kp (64x64) and Ke (0.5, 192x192) per batch.
// ---------------------------------------------------------------------------
__global__ __launch_bounds__(256) void gemm_sim(const float* __restrict__ hbuf,
                                                float* __restrict__ Kp,
                                                float* __restrict__ Ke)
{
    const int id = blockIdx.x, b = blockIdx.y, t = threadIdx.x;
    int mt, nt, ldo; const float *X, *Y; float* outp; float scale;
    if (id < 4) {
        mt = (id >> 1) * 32; nt = (id & 1) * 32; ldo = 64;
        X = hbuf + (size_t)b * 64 * kDp;
        Y = hbuf + (512 + (size_t)b * 64) * kDp;
        outp = Kp + (size_t)b * 4096; scale = 1.0f;
    } else {
        int e = id - 4;
        mt = (e / 6) * 32; nt = (e % 6) * 32; ldo = 192;
        X = hbuf + (1024 + (size_t)b * 192) * kDp;
        Y = hbuf + (2560 + (size_t)b * 192) * kDp;
        outp = Ke + (size_t)b * 36864; scale = 0.5f;
    }
    __shared__ float Xs[32][36];
    __shared__ float Ys[32][36];
    const int row = t >> 3, kq = t & 7;
    const int ty = t >> 4, tx = t & 15;
    float acc[2][2] = {};
    for (int k0 = 0; k0 < kDp; k0 += 32) {
        float4 xa = *(const float4*)(X + (size_t)(mt + row) * kDp + k0 + kq * 4);
        float4 ya = *(const float4*)(Y + (size_t)(nt + row) * kDp + k0 + kq * 4);
        Xs[kq * 4 + 0][row] = xa.x; Xs[kq * 4 + 1][row] = xa.y;
        Xs[kq * 4 + 2][row] = xa.z; Xs[kq * 4 + 3][row] = xa.w;
        Ys[kq * 4 + 0][row] = ya.x; Ys[kq * 4 + 1][row] = ya.y;
        Ys[kq * 4 + 2][row] = ya.z; Ys[kq * 4 + 3][row] = ya.w;
        __syncthreads();
#pragma unroll
        for (int kk = 0; kk < 32; ++kk) {
            float2 xv = *(const float2*)&Xs[kk][ty * 2];
            float2 yv = *(const float2*)&Ys[kk][tx * 2];
            acc[0][0] += xv.x * yv.x; acc[0][1] += xv.x * yv.y;
            acc[1][0] += xv.y * yv.x; acc[1][1] += xv.y * yv.y;
        }
        __syncthreads();
    }
#pragma unroll
    for (int i = 0; i < 2; ++i)
#pragma unroll
        for (int j = 0; j < 2; ++j)
            outp[(size_t)(mt + ty * 2 + i) * ldo + nt + tx * 2 + j] = scale * acc[i][j];
}

// ---------------------------------------------------------------------------
// Per-batch: source-node CSR + class reps via LDS atomicMin keymaps + class-CSR.
// Also zeroes this batch's degcnt slice (verified R6).
// ---------------------------------------------------------------------------
__global__ __launch_bounds__(256) void build_csr(
    const int* __restrict__ s1, const int* __restrict__ d1,
    const int* __restrict__ s2, const int* __restrict__ d2,
    int* __restrict__ off1, int* __restrict__ lst1,
    int* __restrict__ off2, int* __restrict__ lst2,
    int* __restrict__ rep1g, int* __restrict__ rep2g,
    int* __restrict__ coff1, int* __restrict__ clst1,
    int* __restrict__ coff2, int* __restrict__ clst2,
    int* __restrict__ degcnt)
{
    int b = blockIdx.x, t = threadIdx.x;
    __shared__ int km1[4096], km2[4096];
    __shared__ short es1[kE], es2[kE];
    __shared__ short rp1[kE], rp2[kE];
    __shared__ int cnt1[64], cnt2[64], pos1[64], pos2[64];
    __shared__ int ccnt1[kE], ccnt2[kE], cpos1[kE], cpos2[kE];

    for (int i = t; i < 4096; i += 256) {
        km1[i] = 0x7fffffff; km2[i] = 0x7fffffff;
        degcnt[b * kNN + i] = 0;
    }
    if (t < 64) { cnt1[t] = 0; cnt2[t] = 0; }
    for (int i = t; i < kE; i += 256) { ccnt1[i] = 0; ccnt2[i] = 0; }
    __syncthreads();

    if (t < kE) {
        int v1 = s1[b * kE + t], v2 = s2[b * kE + t];
        es1[t] = (short)v1; es2[t] = (short)v2;
        atomicAdd(&cnt1[v1], 1);
        atomicAdd(&cnt2[v2], 1);
        atomicMin(&km1[v1 * 64 + d1[b * kE + t]], t);
        atomicMin(&km2[v2 * 64 + d2[b * kE + t]], t);
    }
    __syncthreads();

    if (t < kE) {
        int r1 = km1[es1[t] * 64 + d1[b * kE + t]];
        int r2 = km2[es2[t] * 64 + d2[b * kE + t]];
        rp1[t] = (short)r1; rp2[t] = (short)r2;
        rep1g[b * kE + t] = r1; rep2g[b * kE + t] = r2;
        atomicAdd(&ccnt1[r1], 1);
        atomicAdd(&ccnt2[r2], 1);
    }
    __syncthreads();

    if (t == 0) {
        int a = 0, c = 0;
        for (int v = 0; v < 64; ++v) { pos1[v] = a; a += cnt1[v]; pos2[v] = c; c += cnt2[v]; }
        a = 0; c = 0;
        for (int v = 0; v < kE; ++v) { cpos1[v] = a; a += ccnt1[v]; cpos2[v] = c; c += ccnt2[v]; }
    }
    __syncthreads();

    if (t < 64) { off1[b * 65 + t] = pos1[t]; off2[b * 65 + t] = pos2[t]; }
    if (t == 0) { off1[b * 65 + 64] = kE; off2[b * 65 + 64] = kE; }
    if (t < kE) { coff1[b * 193 + t] = cpos1[t]; coff2[b * 193 + t] = cpos2[t]; }
    if (t == 0) { coff1[b * 193 + kE] = kE; coff2[b * 193 + kE] = kE; }
    __syncthreads();

    if (t < kE) {
        int p = atomicAdd(&pos1[es1[t]], 1); lst1[b * kE + p] = t;
        int q = atomicAdd(&pos2[es2[t]], 1); lst2[b * kE + q] = t;
        int cp = atomicAdd(&cpos1[rp1[t]], 1); clst1[b * kE + cp] = t;
        int cq = atomicAdd(&cpos2[rp2[t]], 1); clst2[b * kE + cq] = t;
    }
}

// ---------------------------------------------------------------------------
// Degree count: one thread per (i,j) pair (verified R4-R6)
// ---------------------------------------------------------------------------
__global__ __launch_bounds__(256) void pairdeg(
    const int* __restrict__ s1, const int* __restrict__ d1,
    const int* __restrict__ s2, const int* __restrict__ d2,
    const int* __restrict__ rep1g, const int* __restrict__ rep2g,
    const int* __restrict__ coff1, const int* __restrict__ clst1,
    const int* __restrict__ coff2, const int* __restrict__ clst2,
    const float* __restrict__ Ke, int* __restrict__ degcnt)
{
    const int b = blockIdx.y, t = threadIdx.x;
    __shared__ short rs1[kE], rd1[kE], rs2[kE], rd2[kE];
    __shared__ short rp1[kE], rp2[kE];
    __shared__ int co1[kE + 1], co2[kE + 1];
    __shared__ short cl1[kE], cl2[kE];

    for (int i = t; i < kE; i += 256) {
        rs1[i] = (short)s1[b * kE + i]; rd1[i] = (short)d1[b * kE + i];
        rs2[i] = (short)s2[b * kE + i]; rd2[i] = (short)d2[b * kE + i];
        rp1[i] = (short)rep1g[b * kE + i]; rp2[i] = (short)rep2g[b * kE + i];
        cl1[i] = (short)clst1[b * kE + i]; cl2[i] = (short)clst2[b * kE + i];
    }
    for (int i = t; i < kE + 1; i += 256) {
        co1[i] = coff1[b * 193 + i]; co2[i] = coff2[b * 193 + i];
    }
    __syncthreads();

    int idx = blockIdx.x * 256 + t;
    if (idx >= kE * kE) return;
    int i = idx / kE, j = idx - i * kE;
    if (rp1[i] != i || rp2[j] != j) return;

    const float* Keb = Ke + (size_t)b * kE * kE;
    float sum = 0.f;
    for (int m = co1[i]; m < co1[i + 1]; ++m) {
        int ii = cl1[m];
        const float* kr = Keb + (size_t)ii * kE;
        for (int n = co2[j]; n < co2[j + 1]; ++n) sum += kr[cl2[n]];
    }
    int r = rs2[j] * 64 + rs1[i];
    int c = rd2[j] * 64 + rd1[i];
    if (r != c && sum > 0.0f) atomicAdd(&degcnt[b * kNN + r], 1);
}

// ---------------------------------------------------------------------------
// Fused message-gather + layer MLP. kd/deg computed inline from Kp/degcnt
// (kdiag[b][row] == Kp[b][row&63][row>>6]; layer0 x == Kp^T — verified R7/R8
// phase code). Everything else identical to R6.
// ---------------------------------------------------------------------------
template <int C>
__global__ __launch_bounds__(256) void layer_k(
    const int* __restrict__ off1, const int* __restrict__ lst1,
    const int* __restrict__ off2, const int* __restrict__ lst2,
    const int* __restrict__ d1, const int* __restrict__ d2,
    const float* __restrict__ Ke, const float* __restrict__ x,
    const float* __restrict__ Kp, const int* __restrict__ degcnt,
    const float* __restrict__ W, const float* __restrict__ bb,
    const float* __restrict__ S, const float* __restrict__ c0,
    float* __restrict__ xn, float* __restrict__ vbuf)
{
    const int r2 = blockIdx.x, b = blockIdx.y, t = threadIdx.x;
    __shared__ float WL[C * 16];
    __shared__ float bL[16], SL[16];
    __shared__ float c0v;
    __shared__ int jd2[kE];
    __shared__ int il[kE];
    __shared__ float msgT[64][18];

    for (int k = t; k < C * 16; k += 256) WL[k] = W[k];
    if (t < 16) { bL[t] = bb[t]; SL[t] = S[t]; }
    if (t == 0) c0v = c0[0];
    const int j0 = off2[b * 65 + r2];
    const int n2 = off2[b * 65 + r2 + 1] - j0;
    for (int k = t; k < n2; k += 256) {
        int j = lst2[b * kE + j0 + k];
        jd2[k] = (j << 8) | d2[b * kE + j];
    }
    for (int k = t; k < kE; k += 256) {
        int i = lst1[b * kE + k];
        il[k] = (i << 8) | d1[b * kE + i];
    }
    __syncthreads();

    const int r1 = t >> 2, lane = t & 3;
    const int i0 = off1[b * 65 + r1], i1 = off1[b * 65 + r1 + 1];
    const float* Keb = Ke + (size_t)b * kE * kE;
    const float* KpB = Kp + (size_t)b * kNN;

    if (C == 1) {
        // gather from Kp^T: x[dd2*64+dd1] == Kp[b][dd1][dd2]
        float acc = 0.f;
        for (int k = 0; k < n2; ++k) {
            int pk = jd2[k], j = pk >> 8, dd2 = pk & 255;
            for (int m = i0 + lane; m < i1; m += 4) {
                int pi = il[m], i = pi >> 8, dd1 = pi & 255;
                if (dd2 == r2 && dd1 == r1) continue;
                acc += Keb[(size_t)i * kE + j] * KpB[dd1 * 64 + dd2];
            }
        }
        acc += __shfl_xor(acc, 1);
        acc += __shfl_xor(acc, 2);
        if (lane == 0) msgT[r1][0] = acc;
    } else {
        const float* xb = x + (size_t)b * kNN * C;
        constexpr int NCH = (C + 3) / 4;
        float acc[NCH];
#pragma unroll
        for (int cc = 0; cc < NCH; ++cc) acc[cc] = 0.f;
        for (int k = 0; k < n2; ++k) {
            int pk = jd2[k], j = pk >> 8, dd2 = pk & 255;
            const float* xrow = xb + (size_t)(dd2 * 64) * C;
            for (int m = i0; m < i1; ++m) {
                int pi = il[m], i = pi >> 8, dd1 = pi & 255;
                if (dd2 == r2 && dd1 == r1) continue;
                float kv = Keb[(size_t)i * kE + j];
                const float* xc = xrow + dd1 * C;
#pragma unroll
                for (int cc = 0; cc < NCH; ++cc) {
                    int c = lane + cc * 4;
                    if (c < C) acc[cc] += kv * xc[c];
                }
            }
        }
#pragma unroll
        for (int cc = 0; cc < NCH; ++cc) {
            int c = lane + cc * 4;
            if (c < C) msgT[r1][c] = acc[cc];
        }
    }
    __syncthreads();

    const int row = r2 * 64 + r1;
    const int idx = b * kNN + row;
    const float kd = KpB[r1 * 64 + r2];          // kdiag[b][row]
    const float dg = fmaxf((float)(degcnt[idx] + (kd > 0.f ? 1 : 0)), 1.f);
    float m[C];
    if (C == 1) {
        m[0] = (msgT[r1][0] + kd * kd) / dg;     // x[row] == kd for layer 0
    } else {
        const float* xr = x + (size_t)idx * C;
#pragma unroll
        for (int c = 0; c < C; ++c)
            m[c] = (msgT[r1][c] + kd * xr[c]) / dg;
    }
    float vpart = 0.f;
#pragma unroll
    for (int ff = 0; ff < 4; ++ff) {
        int f = lane * 4 + ff;
        float a = bL[f];
#pragma unroll
        for (int c = 0; c < C; ++c) a += m[c] * WL[c * 16 + f];
        float h = fmaxf(a, 0.f);
        xn[(size_t)idx * 17 + f] = h;
        vpart += h * SL[f];
    }
    vpart += __shfl_xor(vpart, 1);
    vpart += __shfl_xor(vpart, 2);
    if (lane == 0) vbuf[idx] = vpart + c0v;
}

// ---------------------------------------------------------------------------
// Sinkhorn via dual potentials (verified R5/R6)
// ---------------------------------------------------------------------------
template <int NR, int THREADS, bool FINAL>
__global__ __launch_bounds__(THREADS) void sinkhorn_k(
    const float* __restrict__ vin, float* __restrict__ outp,
    const float* __restrict__ binvp, const float* __restrict__ Wc,
    const float* __restrict__ bc)
{
    constexpr int MAXK = (NR + 7) / 8;
    __shared__ float mat[NR][68];
    __shared__ float fL[NR], gL[NR];
    __shared__ float WcL[17];
    __shared__ float bcv, binvv;
    const int b = blockIdx.x, tid = threadIdx.x;

    if (FINAL) {
        if (tid < 17) WcL[tid] = Wc[tid];
        if (tid == 17) bcv = bc[0];
        if (tid == 18) binvv = binvp[0];
        __syncthreads();
    }
    for (int idx = tid; idx < NR * NR; idx += THREADS) {
        int q = idx / NR, p = idx - q * NR;
        float val;
        if (FINAL) {
            if (p < kN && q < kN) {
                const float* xr = vin + (size_t)(b * kNN + q * kN + p) * 17;
                float v = bcv;
#pragma unroll
                for (int c = 0; c < 17; ++c) v += xr[c] * WcL[c];
                val = v;
            } else val = binvv;
        } else {
            val = vin[b * kNN + q * kN + p] * kTauInv;
        }
        mat[p][q] = val;
    }
    if (tid < NR) { fL[tid] = 0.f; gL[tid] = 0.f; }
    __syncthreads();

    const int r = tid >> 3, s = tid & 7;
    const bool act = r < NR;
    const int cnt = act ? ((NR - s + 7) >> 3) : 0;
    float Lrow[MAXK], Lcol[MAXK];
    for (int k = 0; k < cnt; ++k) {
        Lrow[k] = mat[r][s + 8 * k];
        Lcol[k] = mat[s + 8 * k][r];
    }
    __syncthreads();

    float tv[MAXK];
    for (int it = 0; it < 10; ++it) {
        float mx = -1e30f;
        for (int k = 0; k < cnt; ++k) { tv[k] = Lrow[k] + gL[s + 8 * k]; mx = fmaxf(mx, tv[k]); }
        mx = fmaxf(mx, __shfl_xor(mx, 1));
        mx = fmaxf(mx, __shfl_xor(mx, 2));
        mx = fmaxf(mx, __shfl_xor(mx, 4));
        float sum = 0.f;
        for (int k = 0; k < cnt; ++k) sum += __expf(tv[k] - mx);
        sum += __shfl_xor(sum, 1);
        sum += __shfl_xor(sum, 2);
        sum += __shfl_xor(sum, 4);
        if (act && s == 0) fL[r] = -(mx + __logf(sum));
        __syncthreads();
        mx = -1e30f;
        for (int k = 0; k < cnt; ++k) { tv[k] = Lcol[k] + fL[s + 8 * k]; mx = fmaxf(mx, tv[k]); }
        mx = fmaxf(mx, __shfl_xor(mx, 1));
        mx = fmaxf(mx, __shfl_xor(mx, 2));
        mx = fmaxf(mx, __shfl_xor(mx, 4));
        sum = 0.f;
        for (int k = 0; k < cnt; ++k) sum += __expf(tv[k] - mx);
        sum += __shfl_xor(sum, 1);
        sum += __shfl_xor(sum, 2);
        sum += __shfl_xor(sum, 4);
        if (act && s == 0) gL[r] = -(mx + __logf(sum));
        __syncthreads();
    }

    if (act) {
        float fr = fL[r];
        for (int k = 0; k < cnt; ++k) {
            int q = s + 8 * k, p = r;
            float e = __expf(Lrow[k] + fr + gL[q]);
            if (FINAL) {
                if (p < kN && q < kN) outp[((size_t)b * kN + p) * kN + q] = e;
            } else {
                outp[(size_t)(b * kNN + q * kN + p) * 17 + 16] = e;
            }
        }
    }
}

// ---------------------------------------------------------------------------
// Single-block global max + normalize (verified R6).
// ---------------------------------------------------------------------------
__global__ __launch_bounds__(1024) void norm_out(float* __restrict__ outp)
{
    const int t = threadIdx.x;
    float4 v[8];
    float mx = -1e30f;
#pragma unroll
    for (int i = 0; i < 8; ++i) {
        v[i] = ((const float4*)outp)[t + i * 1024];
        mx = fmaxf(mx, fmaxf(fmaxf(v[i].x, v[i].y), fmaxf(v[i].z, v[i].w)));
    }
#pragma unroll
    for (int o = 32; o >= 1; o >>= 1) mx = fmaxf(mx, __shfl_xor(mx, o));
    __shared__ float wmax[16];
    if ((t & 63) == 0) wmax[t >> 6] = mx;
    __syncthreads();
    if (t < 16) {
        float m2 = wmax[t];
#pragma unroll
        for (int o = 8; o >= 1; o >>= 1) m2 = fmaxf(m2, __shfl_xor(m2, o));
        if (t == 0) wmax[0] = m2;
    }
    __syncthreads();
    float inv = 1.0f / wmax[0];
#pragma unroll
    for (int i = 0; i < 8; ++i) {
        float4 r;
        r.x = v[i].x * inv; r.y = v[i].y * inv;
        r.z = v[i].z * inv; r.w = v[i].w * inv;
        ((float4*)outp)[t + i * 1024] = r;
    }
}

// ---------------------------------------------------------------------------
extern "C" void kernel_launch(void* const* d_in, const int* in_sizes, int n_in,
                              void* d_out, int out_size, void* d_ws, size_t ws_size,
                              hipStream_t stream)
{
    (void)in_sizes; (void)n_in; (void)out_size; (void)ws_size;

    const float* x1    = (const float*)d_in[0];
    const float* x2    = (const float*)d_in[1];
    const float* e1    = (const float*)d_in[2];
    const float* e2    = (const float*)d_in[3];
    const float* Wp    = (const float*)d_in[4];
    const float* bp    = (const float*)d_in[5];
    const float* gamma = (const float*)d_in[6];
    const float* beta  = (const float*)d_in[7];
    const float* W0 = (const float*)d_in[8];
    const float* b0 = (const float*)d_in[9];
    const float* S0 = (const float*)d_in[10];
    const float* c0 = (const float*)d_in[11];
    const float* W1 = (const float*)d_in[12];
    const float* b1 = (const float*)d_in[13];
    const float* S1 = (const float*)d_in[14];
    const float* c1 = (const float*)d_in[15];
    const float* W2 = (const float*)d_in[16];
    const float* b2 = (const float*)d_in[17];
    const float* S2 = (const float*)d_in[18];
    const float* c2 = (const float*)d_in[19];
    const float* Wc = (const float*)d_in[20];
    const float* bc = (const float*)d_in[21];
    const float* binv = (const float*)d_in[22];
    const int* src1 = (const int*)d_in[23];
    const int* dst1 = (const int*)d_in[24];
    const int* src2 = (const int*)d_in[25];
    const int* dst2 = (const int*)d_in[26];

    float* out = (float*)d_out;
    float* wsf = (float*)d_ws;

    float* hbuf  = wsf;                    // 1,048,576
    float* P     = hbuf + 1048576;         // 4,194,304
    float* Kp    = P + 4194304;            // 32768
    float* Ke    = Kp + 32768;             // 294912
    float* vbuf  = Ke + 294912;            // 32768
    float* xA    = vbuf + 32768;           // 557056
    float* xB    = xA + 557056;            // 557056
    float* stats = xB + 557056;            // 2048
    int*   degcnt = (int*)(stats + 2048);  // 32768
    int*   off1 = degcnt + 32768;          // 520
    int*   off2 = off1 + 520;              // 520
    int*   lst1 = off2 + 520;              // 1536
    int*   lst2 = lst1 + 1536;             // 1536
    int*   rep1g = lst2 + 1536;            // 1536
    int*   rep2g = rep1g + 1536;           // 1536
    int*   coff1 = rep2g + 1536;           // 1544
    int*   coff2 = coff1 + 1544;           // 1544
    int*   clst1 = coff2 + 1544;           // 1536
    int*   clst2 = clst1 + 1536;           // 1536

    // ---- projection GEMM (zeroes stats) + fused reduce+bias+stats ----
    gemm_proj<<<dim3(4, 64, 4), 256, 0, stream>>>(x1, x2, e1, e2, Wp, P, stats);
    reduce_bias_stats<<<256, 256, 0, stream>>>(P, bp, hbuf, stats);

    // ---- batchnorm + relu + l2norm ----
    bn_norm_l2<<<4096, 256, 0, stream>>>(hbuf, stats, gamma, beta);

    // ---- similarity GEMMs ----
    gemm_sim<<<dim3(40, 8), 256, 0, stream>>>(hbuf, Kp, Ke);

    // ---- sparse K structure (build_csr zeroes degcnt) ----
    build_csr<<<8, 256, 0, stream>>>(src1, dst1, src2, dst2,
                                     off1, lst1, off2, lst2,
                                     rep1g, rep2g, coff1, clst1, coff2, clst2,
                                     degcnt);
    pairdeg<<<dim3(144, 8), 256, 0, stream>>>(src1, dst1, src2, dst2,
                                              rep1g, rep2g, coff1, clst1, coff2, clst2,
                                              Ke, degcnt);

    // ---- GNN layers (fused gather+MLP, kd/deg inline) + sinkhorns ----
    layer_k<1><<<dim3(64, 8), 256, 0, stream>>>(off1, lst1, off2, lst2, dst1, dst2,
                                                Ke, nullptr, Kp, degcnt, W0, b0, S0, c0, xA, vbuf);
    sinkhorn_k<64, 512, false><<<8, 512, 0, stream>>>(vbuf, xA, nullptr, nullptr, nullptr);

    layer_k<17><<<dim3(64, 8), 256, 0, stream>>>(off1, lst1, off2, lst2, dst1, dst2,
                                                 Ke, xA, Kp, degcnt, W1, b1, S1, c1, xB, vbuf);
    sinkhorn_k<64, 512, false><<<8, 512, 0, stream>>>(vbuf, xB, nullptr, nullptr, nullptr);

    layer_k<17><<<dim3(64, 8), 256, 0, stream>>>(off1, lst1, off2, lst2, dst1, dst2,
                                                 Ke, xB, Kp, degcnt, W2, b2, S2, c2, xA, vbuf);
    sinkhorn_k<64, 512, false><<<8, 512, 0, stream>>>(vbuf, xA, nullptr, nullptr, nullptr);

    // ---- final: fused projection + bin-augmented sinkhorn + normalize ----
    sinkhorn_k<65, 576, true><<<8, 576, 0, stream>>>(xA, out, binv, Wc, bc);
    norm_out<<<1, 1024, 0, stream>>>(out);
}